// Round 3
// baseline (2948.677 us; speedup 1.0000x reference)
//
#include <hip/hip_runtime.h>
#include <hip/hip_bf16.h>

#define HDIM 128
#define NREL 16
#define NBASES 8
#define LDSPAD 136  // 128+8 shorts: rows 16B-aligned, 2-way bank alias (free per m136)

typedef short bf16x8 __attribute__((ext_vector_type(8)));
typedef short s16x4 __attribute__((ext_vector_type(4)));
typedef float f32x4 __attribute__((ext_vector_type(4)));

static __device__ __forceinline__ short f2bf(float x) {
    __hip_bfloat16 b = __float2bfloat16(x);
    return *(short*)&b;
}

// ---------------- weight prep (fp32 in -> bf16 out) ----------------
// wt[r][o][i] = W_r[i][o] = sum_b wcomp[r][b] * basis[b][i][o]
__global__ void compute_wt(const float* __restrict__ basis,
                           const float* __restrict__ wcomp,
                           short* __restrict__ wt) {
    int ro = blockIdx.x;
    int r = ro >> 7, o = ro & 127;
    int i = threadIdx.x;
    float acc = 0.f;
#pragma unroll
    for (int b = 0; b < NBASES; ++b)
        acc += wcomp[r * NBASES + b] * basis[(b * HDIM + i) * HDIM + o];
    wt[(size_t)(r * HDIM + o) * HDIM + i] = f2bf(acc);
}

// lwT[o][i] = loop_w[i][o]  (fp32 -> bf16)
__global__ void transpose128(const float* __restrict__ in, short* __restrict__ out) {
    int o = blockIdx.x, i = threadIdx.x;
    out[o * HDIM + i] = f2bf(in[i * HDIM + o]);
}

// fp32 -> bf16 cast (vectorized)
__global__ void cast_bf16(const float* __restrict__ in, short* __restrict__ out, int n4) {
    for (int i = blockIdx.x * blockDim.x + threadIdx.x; i < n4; i += gridDim.x * blockDim.x) {
        f32x4 v = ((const f32x4*)in)[i];
        s16x4 o;
#pragma unroll
        for (int j = 0; j < 4; ++j) o[j] = f2bf(v[j]);
        ((s16x4*)out)[i] = o;
    }
}

// ---------------- edge bucketing ----------------
__global__ void hist_rel(const int* __restrict__ rel, int n, int* __restrict__ cnt) {
    __shared__ int h[NREL];
    if (threadIdx.x < NREL) h[threadIdx.x] = 0;
    __syncthreads();
    for (int e = blockIdx.x * blockDim.x + threadIdx.x; e < n; e += gridDim.x * blockDim.x)
        atomicAdd(&h[rel[e]], 1);
    __syncthreads();
    if (threadIdx.x < NREL) atomicAdd(&cnt[threadIdx.x], h[threadIdx.x]);
}

// meta ints: [0..15] cnt, [16..32] offs, [33..48] cursor, [49..65] tileOff, [66] ntiles
__global__ void scan_rel(int* __restrict__ meta) {
    int* cnt = meta;
    int* offs = meta + 16;
    int* cursor = meta + 33;
    int* tileOff = meta + 49;
    int o = 0, t = 0;
    for (int r = 0; r < NREL; ++r) {
        offs[r] = o; cursor[r] = o; tileOff[r] = t;
        o += cnt[r];
        t += (cnt[r] + 127) >> 7;
    }
    offs[NREL] = o;
    tileOff[NREL] = t;
    meta[66] = t;
}

__global__ void scatter_edges(const int* __restrict__ src, const int* __restrict__ dst,
                              const int* __restrict__ rel, int n,
                              int* __restrict__ cursor,
                              int* __restrict__ src_s, int* __restrict__ dst_s) {
    int tid = blockIdx.x * blockDim.x + threadIdx.x;
    int stride = gridDim.x * blockDim.x;
    int lane = threadIdx.x & 63;
    for (int e0 = 0; e0 < n; e0 += stride) {
        int e = e0 + tid;
        bool act = e < n;
        int r = act ? rel[e] : -1;
        int s = act ? src[e] : 0;
        int d = act ? dst[e] : 0;
#pragma unroll 1
        for (int rr = 0; rr < NREL; ++rr) {
            unsigned long long m = __ballot(r == rr);
            if (m == 0ull) continue;
            int leader = __ffsll((long long)m) - 1;
            int base = 0;
            if (lane == leader) base = atomicAdd(&cursor[rr], __popcll(m));
            base = __shfl(base, leader);
            if (r == rr) {
                int p = base + __popcll(m & ((1ull << lane) - 1ull));
                src_s[p] = s;
                dst_s[p] = d;
            }
        }
    }
}

// ---------------- self-loop GEMM: out = h @ loop_w + bias (fp32 store) ----------------
__global__ __launch_bounds__(256) void self_gemm(
    const short* __restrict__ h,    // bf16 [M,128]
    const short* __restrict__ bT,   // bf16 [o][i] = loop_w[i][o]
    const float* __restrict__ bias, // fp32 [128]
    float* __restrict__ out, int M) {
    __shared__ short As[128 * LDSPAD];
    int tid = threadIdx.x;
    int row0 = blockIdx.x * 128;
    int wave = tid >> 6, lane = tid & 63;
    int mq = (wave & 1) * 64, nq = (wave >> 1) * 64;
    int lr = lane & 15, quad = lane >> 4;

    // B fragments from global (L2-hot): B[k][n], n = nq+ni*16+lr, k = kk*32+quad*8+j
    bf16x8 b[4][4];
#pragma unroll
    for (int kk = 0; kk < 4; ++kk)
#pragma unroll
        for (int ni = 0; ni < 4; ++ni)
            b[kk][ni] = *(const bf16x8*)(bT + (nq + ni * 16 + lr) * HDIM + kk * 32 + quad * 8);

    int lane16 = tid & 15, rsub = tid >> 4;
#pragma unroll
    for (int p = 0; p < 8; ++p) {
        int row = p * 16 + rsub;
        int g = row0 + row;
        bf16x8 va = (bf16x8)0;
        if (g < M) va = *(const bf16x8*)(h + (size_t)g * HDIM + lane16 * 8);
        *(bf16x8*)(As + row * LDSPAD + lane16 * 8) = va;
    }
    __syncthreads();

    f32x4 acc[4][4] = {};
#pragma unroll
    for (int kk = 0; kk < 4; ++kk) {
        int kb = kk * 32 + quad * 8;
        bf16x8 a[4];
#pragma unroll
        for (int mi = 0; mi < 4; ++mi)
            a[mi] = *(const bf16x8*)(As + (mq + mi * 16 + lr) * LDSPAD + kb);
#pragma unroll
        for (int mi = 0; mi < 4; ++mi)
#pragma unroll
            for (int ni = 0; ni < 4; ++ni)
                acc[mi][ni] = __builtin_amdgcn_mfma_f32_16x16x32_bf16(a[mi], b[kk][ni], acc[mi][ni], 0, 0, 0);
    }
    // C/D: col = lane&15 (n), row = quad*4 + reg (m)  [m89]
#pragma unroll
    for (int mi = 0; mi < 4; ++mi) {
#pragma unroll
        for (int reg = 0; reg < 4; ++reg) {
            int g = row0 + mq + mi * 16 + quad * 4 + reg;
            if (g < M) {
#pragma unroll
                for (int ni = 0; ni < 4; ++ni) {
                    int n = nq + ni * 16 + lr;
                    out[(size_t)g * HDIM + n] = acc[mi][ni][reg] + bias[n];
                }
            }
        }
    }
}

// ---------------- edge GEMM: out[dst] += h[src] @ W_r (atomic fp32 epilogue) ----------------
__global__ __launch_bounds__(256) void edge_gemm(
    const short* __restrict__ h,
    const short* __restrict__ wt,   // bf16 [16][o][i]
    const int* __restrict__ meta,
    const int* __restrict__ src_s, const int* __restrict__ dst_s,
    float* __restrict__ out) {
    int t = blockIdx.x;
    if (t >= meta[66]) return;
    const int* offs = meta + 16;
    const int* tileOff = meta + 49;
    int r = 0;
    while (r < NREL - 1 && t >= tileOff[r + 1]) ++r;
    int e0 = offs[r] + (t - tileOff[r]) * 128;
    int eEnd = offs[r + 1];

    __shared__ short As[128 * LDSPAD];
    __shared__ int dloc[128];
    int tid = threadIdx.x;
    int wave = tid >> 6, lane = tid & 63;
    int mq = (wave & 1) * 64, nq = (wave >> 1) * 64;
    int lr = lane & 15, quad = lane >> 4;

    const short* wr = wt + (size_t)r * HDIM * HDIM;
    bf16x8 b[4][4];
#pragma unroll
    for (int kk = 0; kk < 4; ++kk)
#pragma unroll
        for (int ni = 0; ni < 4; ++ni)
            b[kk][ni] = *(const bf16x8*)(wr + (nq + ni * 16 + lr) * HDIM + kk * 32 + quad * 8);

    int lane16 = tid & 15, rsub = tid >> 4;
#pragma unroll
    for (int p = 0; p < 8; ++p) {
        int row = p * 16 + rsub;
        int e = e0 + row;
        bf16x8 va = (bf16x8)0;
        if (e < eEnd) {
            int s = src_s[e];
            va = *(const bf16x8*)(h + (size_t)s * HDIM + lane16 * 8);
        }
        *(bf16x8*)(As + row * LDSPAD + lane16 * 8) = va;
    }
    if (tid < 128) {
        int e = e0 + tid;
        dloc[tid] = (e < eEnd) ? dst_s[e] : -1;
    }
    __syncthreads();

    f32x4 acc[4][4] = {};
#pragma unroll
    for (int kk = 0; kk < 4; ++kk) {
        int kb = kk * 32 + quad * 8;
        bf16x8 a[4];
#pragma unroll
        for (int mi = 0; mi < 4; ++mi)
            a[mi] = *(const bf16x8*)(As + (mq + mi * 16 + lr) * LDSPAD + kb);
#pragma unroll
        for (int mi = 0; mi < 4; ++mi)
#pragma unroll
            for (int ni = 0; ni < 4; ++ni)
                acc[mi][ni] = __builtin_amdgcn_mfma_f32_16x16x32_bf16(a[mi], b[kk][ni], acc[mi][ni], 0, 0, 0);
    }
#pragma unroll
    for (int mi = 0; mi < 4; ++mi) {
#pragma unroll
        for (int reg = 0; reg < 4; ++reg) {
            int m = mq + mi * 16 + quad * 4 + reg;
            int d = dloc[m];
            if (d >= 0) {
#pragma unroll
                for (int ni = 0; ni < 4; ++ni) {
                    int n = nq + ni * 16 + lr;
                    atomicAdd(&out[(size_t)d * HDIM + n], acc[mi][ni][reg]);
                }
            }
        }
    }
}

// ---------------- finalize: relu -> bf16 (intermediate h1) ----------------
__global__ void finalize_relu_bf16(const float* __restrict__ in, short* __restrict__ out, int n4) {
    for (int i = blockIdx.x * blockDim.x + threadIdx.x; i < n4; i += gridDim.x * blockDim.x) {
        f32x4 v = ((const f32x4*)in)[i];
        s16x4 o;
#pragma unroll
        for (int j = 0; j < 4; ++j) o[j] = f2bf(v[j] > 0.f ? v[j] : 0.f);
        ((s16x4*)out)[i] = o;
    }
}

// ---------------- finalize: relu -> fp32 (final output) ----------------
__global__ void finalize_relu_f32(const float* __restrict__ in, float* __restrict__ out, int n4) {
    for (int i = blockIdx.x * blockDim.x + threadIdx.x; i < n4; i += gridDim.x * blockDim.x) {
        f32x4 v = ((const f32x4*)in)[i];
        f32x4 o;
#pragma unroll
        for (int j = 0; j < 4; ++j) o[j] = v[j] > 0.f ? v[j] : 0.f;
        ((f32x4*)out)[i] = o;
    }
}

extern "C" void kernel_launch(void* const* d_in, const int* in_sizes, int n_in,
                              void* d_out, int out_size, void* d_ws, size_t ws_size,
                              hipStream_t stream) {
    // Reference dtypes: all float inputs are fp32; indices int32; output fp32.
    const float* emb    = (const float*)d_in[0];
    const float* basis1 = (const float*)d_in[1];
    const float* wc1    = (const float*)d_in[2];
    const float* lw1    = (const float*)d_in[3];
    const float* bias1  = (const float*)d_in[4];
    const float* basis2 = (const float*)d_in[5];
    const float* wc2    = (const float*)d_in[6];
    const float* lw2    = (const float*)d_in[7];
    const float* bias2  = (const float*)d_in[8];
    const int* src = (const int*)d_in[9];
    const int* dst = (const int*)d_in[10];
    const int* rel = (const int*)d_in[11];

    int n_ent = in_sizes[0] / HDIM;
    int n_edges = in_sizes[9];

    char* ws = (char*)d_ws;
    int* meta = (int*)ws;                          // 1 KB
    short* wt1  = (short*)(ws + 1024);             // 512 KB bf16
    short* wt2  = wt1 + NREL * HDIM * HDIM;        // 512 KB
    short* lw1T = wt2 + NREL * HDIM * HDIM;        // 32 KB
    short* lw2T = lw1T + HDIM * HDIM;              // 32 KB
    short* h0   = lw2T + HDIM * HDIM;              // 12.8 MB bf16 (emb cast)
    short* h1   = h0 + (size_t)n_ent * HDIM;       // 12.8 MB bf16
    int* src_s  = (int*)(h1 + (size_t)n_ent * HDIM); // 3.2 MB
    int* dst_s  = src_s + n_edges;                 // 3.2 MB
    float* out_acc = (float*)(dst_s + n_edges);    // 25.6 MB fp32

    hipMemsetAsync(meta, 0, 1024, stream);

    compute_wt<<<NREL * HDIM, HDIM, 0, stream>>>(basis1, wc1, wt1);
    compute_wt<<<NREL * HDIM, HDIM, 0, stream>>>(basis2, wc2, wt2);
    transpose128<<<HDIM, HDIM, 0, stream>>>(lw1, lw1T);
    transpose128<<<HDIM, HDIM, 0, stream>>>(lw2, lw2T);
    cast_bf16<<<512, 256, 0, stream>>>(emb, h0, n_ent * HDIM / 4);

    hist_rel<<<256, 256, 0, stream>>>(rel, n_edges, meta);
    scan_rel<<<1, 1, 0, stream>>>(meta);
    scatter_edges<<<256, 256, 0, stream>>>(src, dst, rel, n_edges, meta + 33, src_s, dst_s);

    int mtiles = (n_ent + 127) / 128;
    int etiles = (n_edges + 127) / 128 + NREL;

    // layer 1
    self_gemm<<<mtiles, 256, 0, stream>>>(h0, lw1T, bias1, out_acc, n_ent);
    edge_gemm<<<etiles, 256, 0, stream>>>(h0, wt1, meta, src_s, dst_s, out_acc);
    finalize_relu_bf16<<<512, 256, 0, stream>>>(out_acc, h1, n_ent * HDIM / 4);

    // layer 2
    self_gemm<<<mtiles, 256, 0, stream>>>(h1, lw2T, bias2, out_acc, n_ent);
    edge_gemm<<<etiles, 256, 0, stream>>>(h1, wt2, meta, src_s, dst_s, out_acc);
    finalize_relu_f32<<<512, 256, 0, stream>>>(out_acc, (float*)d_out, n_ent * HDIM / 4);
}

// Round 4
// 921.009 us; speedup vs baseline: 3.2016x; 3.2016x over previous
//
#include <hip/hip_runtime.h>
#include <hip/hip_bf16.h>

#define HDIM 128
#define NREL 16
#define NBASES 8
#define LDSPAD 136      // 128+8 shorts: rows 16B-aligned, 2-way bank alias (free per m136)
#define SBLK 512        // scatter blocks (counting-sort chunks)

typedef short bf16x8 __attribute__((ext_vector_type(8)));
typedef short s16x4 __attribute__((ext_vector_type(4)));
typedef float f32x4 __attribute__((ext_vector_type(4)));

static __device__ __forceinline__ short f2bf(float x) {
    __hip_bfloat16 b = __float2bfloat16(x);
    return *(short*)&b;
}

// ---------------- weight prep (fp32 in -> bf16 out) ----------------
// wt[r][o][i] = W_r[i][o] = sum_b wcomp[r][b] * basis[b][i][o]
__global__ void compute_wt(const float* __restrict__ basis,
                           const float* __restrict__ wcomp,
                           short* __restrict__ wt) {
    int ro = blockIdx.x;
    int r = ro >> 7, o = ro & 127;
    int i = threadIdx.x;
    float acc = 0.f;
#pragma unroll
    for (int b = 0; b < NBASES; ++b)
        acc += wcomp[r * NBASES + b] * basis[(b * HDIM + i) * HDIM + o];
    wt[(size_t)(r * HDIM + o) * HDIM + i] = f2bf(acc);
}

// lwT[o][i] = loop_w[i][o]  (fp32 -> bf16)
__global__ void transpose128(const float* __restrict__ in, short* __restrict__ out) {
    int o = blockIdx.x, i = threadIdx.x;
    out[o * HDIM + i] = f2bf(in[i * HDIM + o]);
}

// fp32 -> bf16 cast (vectorized)
__global__ void cast_bf16(const float* __restrict__ in, short* __restrict__ out, int n4) {
    for (int i = blockIdx.x * blockDim.x + threadIdx.x; i < n4; i += gridDim.x * blockDim.x) {
        f32x4 v = ((const f32x4*)in)[i];
        s16x4 o;
#pragma unroll
        for (int j = 0; j < 4; ++j) o[j] = f2bf(v[j]);
        ((s16x4*)out)[i] = o;
    }
}

// ---------------- edge bucketing: contention-free counting sort ----------------
// pass 1: per-block histogram (LDS only, no global atomics)
__global__ __launch_bounds__(256) void hist2(const int* __restrict__ rel, int n, int chunk,
                                             int* __restrict__ blockCnt) {
    __shared__ int h[NREL];
    int tid = threadIdx.x, b = blockIdx.x;
    if (tid < NREL) h[tid] = 0;
    __syncthreads();
    int lo = b * chunk, hi = min(n, lo + chunk);
    for (int e = lo + tid; e < hi; e += blockDim.x) atomicAdd(&h[rel[e]], 1);
    __syncthreads();
    if (tid < NREL) blockCnt[b * NREL + tid] = h[tid];
}

// pass 2: single block. base[b][r] = offs[r] + sum_{b'<b} blockCnt[b'][r]
// meta ints: [16..32] offs, [49..65] tileOff, [66] ntiles  (layout kept from edge_gemm)
__global__ void scan2(const int* __restrict__ blockCnt, int* __restrict__ base,
                      int* __restrict__ meta) {
    __shared__ int tot[NREL];
    int t = threadIdx.x;
    if (t < NREL) {
        int run = 0;
        for (int b = 0; b < SBLK; ++b) {
            base[b * NREL + t] = run;
            run += blockCnt[b * NREL + t];
        }
        tot[t] = run;
    }
    __syncthreads();
    if (t == 0) {
        int* offs = meta + 16;
        int* tileOff = meta + 49;
        int o = 0, tl = 0;
        for (int r = 0; r < NREL; ++r) {
            offs[r] = o; tileOff[r] = tl;
            o += tot[r];
            tl += (tot[r] + 127) >> 7;
        }
        offs[NREL] = o;
        tileOff[NREL] = tl;
        meta[66] = tl;
    }
    __syncthreads();
    if (t < NREL) {
        int off = meta[16 + t];
        for (int b = 0; b < SBLK; ++b) base[b * NREL + t] += off;
    }
}

// pass 3: place edges; per-block LDS cursors — zero contended global atomics
__global__ __launch_bounds__(256) void scatter2(const int* __restrict__ src,
                                                const int* __restrict__ dst,
                                                const int* __restrict__ rel, int n, int chunk,
                                                const int* __restrict__ base,
                                                int* __restrict__ src_s, int* __restrict__ dst_s) {
    __shared__ int cur[NREL];
    int tid = threadIdx.x, b = blockIdx.x;
    if (tid < NREL) cur[tid] = base[b * NREL + tid];
    __syncthreads();
    int lo = b * chunk, hi = min(n, lo + chunk);
    for (int e = lo + tid; e < hi; e += blockDim.x) {
        int r = rel[e];
        int p = atomicAdd(&cur[r], 1);
        src_s[p] = src[e];
        dst_s[p] = dst[e];
    }
}

// ---------------- self-loop GEMM: out = h @ loop_w + bias (fp32 store) ----------------
__global__ __launch_bounds__(256) void self_gemm(
    const short* __restrict__ h,    // bf16 [M,128]
    const short* __restrict__ bT,   // bf16 [o][i] = loop_w[i][o]
    const float* __restrict__ bias, // fp32 [128]
    float* __restrict__ out, int M) {
    __shared__ short As[128 * LDSPAD];
    int tid = threadIdx.x;
    int row0 = blockIdx.x * 128;
    int wave = tid >> 6, lane = tid & 63;
    int mq = (wave & 1) * 64, nq = (wave >> 1) * 64;
    int lr = lane & 15, quad = lane >> 4;

    bf16x8 b[4][4];
#pragma unroll
    for (int kk = 0; kk < 4; ++kk)
#pragma unroll
        for (int ni = 0; ni < 4; ++ni)
            b[kk][ni] = *(const bf16x8*)(bT + (nq + ni * 16 + lr) * HDIM + kk * 32 + quad * 8);

    int lane16 = tid & 15, rsub = tid >> 4;
#pragma unroll
    for (int p = 0; p < 8; ++p) {
        int row = p * 16 + rsub;
        int g = row0 + row;
        bf16x8 va = (bf16x8)0;
        if (g < M) va = *(const bf16x8*)(h + (size_t)g * HDIM + lane16 * 8);
        *(bf16x8*)(As + row * LDSPAD + lane16 * 8) = va;
    }
    __syncthreads();

    f32x4 acc[4][4] = {};
#pragma unroll
    for (int kk = 0; kk < 4; ++kk) {
        int kb = kk * 32 + quad * 8;
        bf16x8 a[4];
#pragma unroll
        for (int mi = 0; mi < 4; ++mi)
            a[mi] = *(const bf16x8*)(As + (mq + mi * 16 + lr) * LDSPAD + kb);
#pragma unroll
        for (int mi = 0; mi < 4; ++mi)
#pragma unroll
            for (int ni = 0; ni < 4; ++ni)
                acc[mi][ni] = __builtin_amdgcn_mfma_f32_16x16x32_bf16(a[mi], b[kk][ni], acc[mi][ni], 0, 0, 0);
    }
    // C/D: col = lane&15 (n), row = quad*4 + reg (m)  [m89]
#pragma unroll
    for (int mi = 0; mi < 4; ++mi) {
#pragma unroll
        for (int reg = 0; reg < 4; ++reg) {
            int g = row0 + mq + mi * 16 + quad * 4 + reg;
            if (g < M) {
#pragma unroll
                for (int ni = 0; ni < 4; ++ni) {
                    int n = nq + ni * 16 + lr;
                    out[(size_t)g * HDIM + n] = acc[mi][ni][reg] + bias[n];
                }
            }
        }
    }
}

// ---------------- edge GEMM: out[dst] += h[src] @ W_r (atomic fp32 epilogue) ----------------
__global__ __launch_bounds__(256) void edge_gemm(
    const short* __restrict__ h,
    const short* __restrict__ wt,   // bf16 [16][o][i]
    const int* __restrict__ meta,
    const int* __restrict__ src_s, const int* __restrict__ dst_s,
    float* __restrict__ out) {
    int t = blockIdx.x;
    if (t >= meta[66]) return;
    const int* offs = meta + 16;
    const int* tileOff = meta + 49;
    int r = 0;
    while (r < NREL - 1 && t >= tileOff[r + 1]) ++r;
    int e0 = offs[r] + (t - tileOff[r]) * 128;
    int eEnd = offs[r + 1];

    __shared__ short As[128 * LDSPAD];
    __shared__ int dloc[128];
    int tid = threadIdx.x;
    int wave = tid >> 6, lane = tid & 63;
    int mq = (wave & 1) * 64, nq = (wave >> 1) * 64;
    int lr = lane & 15, quad = lane >> 4;

    const short* wr = wt + (size_t)r * HDIM * HDIM;
    bf16x8 b[4][4];
#pragma unroll
    for (int kk = 0; kk < 4; ++kk)
#pragma unroll
        for (int ni = 0; ni < 4; ++ni)
            b[kk][ni] = *(const bf16x8*)(wr + (nq + ni * 16 + lr) * HDIM + kk * 32 + quad * 8);

    int lane16 = tid & 15, rsub = tid >> 4;
#pragma unroll
    for (int p = 0; p < 8; ++p) {
        int row = p * 16 + rsub;
        int e = e0 + row;
        bf16x8 va = (bf16x8)0;
        if (e < eEnd) {
            int s = src_s[e];
            va = *(const bf16x8*)(h + (size_t)s * HDIM + lane16 * 8);
        }
        *(bf16x8*)(As + row * LDSPAD + lane16 * 8) = va;
    }
    if (tid < 128) {
        int e = e0 + tid;
        dloc[tid] = (e < eEnd) ? dst_s[e] : -1;
    }
    __syncthreads();

    f32x4 acc[4][4] = {};
#pragma unroll
    for (int kk = 0; kk < 4; ++kk) {
        int kb = kk * 32 + quad * 8;
        bf16x8 a[4];
#pragma unroll
        for (int mi = 0; mi < 4; ++mi)
            a[mi] = *(const bf16x8*)(As + (mq + mi * 16 + lr) * LDSPAD + kb);
#pragma unroll
        for (int mi = 0; mi < 4; ++mi)
#pragma unroll
            for (int ni = 0; ni < 4; ++ni)
                acc[mi][ni] = __builtin_amdgcn_mfma_f32_16x16x32_bf16(a[mi], b[kk][ni], acc[mi][ni], 0, 0, 0);
    }
#pragma unroll
    for (int mi = 0; mi < 4; ++mi) {
#pragma unroll
        for (int reg = 0; reg < 4; ++reg) {
            int m = mq + mi * 16 + quad * 4 + reg;
            int d = dloc[m];
            if (d >= 0) {
#pragma unroll
                for (int ni = 0; ni < 4; ++ni) {
                    int n = nq + ni * 16 + lr;
                    atomicAdd(&out[(size_t)d * HDIM + n], acc[mi][ni][reg]);
                }
            }
        }
    }
}

// ---------------- finalize: relu -> bf16 (intermediate h1) ----------------
__global__ void finalize_relu_bf16(const float* __restrict__ in, short* __restrict__ out, int n4) {
    for (int i = blockIdx.x * blockDim.x + threadIdx.x; i < n4; i += gridDim.x * blockDim.x) {
        f32x4 v = ((const f32x4*)in)[i];
        s16x4 o;
#pragma unroll
        for (int j = 0; j < 4; ++j) o[j] = f2bf(v[j] > 0.f ? v[j] : 0.f);
        ((s16x4*)out)[i] = o;
    }
}

// ---------------- finalize: relu -> fp32 (final output) ----------------
__global__ void finalize_relu_f32(const float* __restrict__ in, float* __restrict__ out, int n4) {
    for (int i = blockIdx.x * blockDim.x + threadIdx.x; i < n4; i += gridDim.x * blockDim.x) {
        f32x4 v = ((const f32x4*)in)[i];
        f32x4 o;
#pragma unroll
        for (int j = 0; j < 4; ++j) o[j] = v[j] > 0.f ? v[j] : 0.f;
        ((f32x4*)out)[i] = o;
    }
}

extern "C" void kernel_launch(void* const* d_in, const int* in_sizes, int n_in,
                              void* d_out, int out_size, void* d_ws, size_t ws_size,
                              hipStream_t stream) {
    const float* emb    = (const float*)d_in[0];
    const float* basis1 = (const float*)d_in[1];
    const float* wc1    = (const float*)d_in[2];
    const float* lw1    = (const float*)d_in[3];
    const float* bias1  = (const float*)d_in[4];
    const float* basis2 = (const float*)d_in[5];
    const float* wc2    = (const float*)d_in[6];
    const float* lw2    = (const float*)d_in[7];
    const float* bias2  = (const float*)d_in[8];
    const int* src = (const int*)d_in[9];
    const int* dst = (const int*)d_in[10];
    const int* rel = (const int*)d_in[11];

    int n_ent = in_sizes[0] / HDIM;
    int n_edges = in_sizes[9];

    char* ws = (char*)d_ws;
    int* meta = (int*)ws;                          // 1 KB
    short* wt1  = (short*)(ws + 1024);             // 512 KB bf16
    short* wt2  = wt1 + NREL * HDIM * HDIM;        // 512 KB
    short* lw1T = wt2 + NREL * HDIM * HDIM;        // 32 KB
    short* lw2T = lw1T + HDIM * HDIM;              // 32 KB
    short* h0   = lw2T + HDIM * HDIM;              // 12.8 MB bf16 (emb cast)
    short* h1   = h0 + (size_t)n_ent * HDIM;       // 12.8 MB bf16
    int* src_s  = (int*)(h1 + (size_t)n_ent * HDIM); // 3.2 MB
    int* dst_s  = src_s + n_edges;                 // 3.2 MB
    float* out_acc = (float*)(dst_s + n_edges);    // 25.6 MB fp32

    // blockCnt/base (2 × SBLK×16 ints = 64 KB) alias onto h1's space: the
    // counting-sort passes complete (stream-serial) before finalize writes h1.
    int* blockCnt = (int*)h1;
    int* baseArr  = blockCnt + SBLK * NREL;

    int chunk = (n_edges + SBLK - 1) / SBLK;

    compute_wt<<<NREL * HDIM, HDIM, 0, stream>>>(basis1, wc1, wt1);
    compute_wt<<<NREL * HDIM, HDIM, 0, stream>>>(basis2, wc2, wt2);
    transpose128<<<HDIM, HDIM, 0, stream>>>(lw1, lw1T);
    transpose128<<<HDIM, HDIM, 0, stream>>>(lw2, lw2T);
    cast_bf16<<<512, 256, 0, stream>>>(emb, h0, n_ent * HDIM / 4);

    hist2<<<SBLK, 256, 0, stream>>>(rel, n_edges, chunk, blockCnt);
    scan2<<<1, 64, 0, stream>>>(blockCnt, baseArr, meta);
    scatter2<<<SBLK, 256, 0, stream>>>(src, dst, rel, n_edges, chunk, baseArr, src_s, dst_s);

    int mtiles = (n_ent + 127) / 128;
    int etiles = (n_edges + 127) / 128 + NREL;

    // layer 1
    self_gemm<<<mtiles, 256, 0, stream>>>(h0, lw1T, bias1, out_acc, n_ent);
    edge_gemm<<<etiles, 256, 0, stream>>>(h0, wt1, meta, src_s, dst_s, out_acc);
    finalize_relu_bf16<<<512, 256, 0, stream>>>(out_acc, h1, n_ent * HDIM / 4);

    // layer 2
    self_gemm<<<mtiles, 256, 0, stream>>>(h1, lw2T, bias2, out_acc, n_ent);
    edge_gemm<<<etiles, 256, 0, stream>>>(h1, wt2, meta, src_s, dst_s, out_acc);
    finalize_relu_f32<<<512, 256, 0, stream>>>(out_acc, (float*)d_out, n_ent * HDIM / 4);
}